// Round 7
// baseline (351.230 us; speedup 1.0000x reference)
//
#include <hip/hip_runtime.h>
#include <stdint.h>

// ---------------------------------------------------------------------------
// Attention: out = softmax(Q K^T) V,  N=8, S=2048, E=512, fp32 in/out.
// R7 = R6 + manual cross-phase prefetch (the R4 idea, now that R4/R5's real
// bug — pre-pass tensor-bit leak — is fixed): K(t+1) double-buffered and V(t)
// issued right after S-MFMA(t), pinned before b1 by the asm memory clobber,
// consumed a phase (or full tile) later. Exposes ~0 global latency per tile.
// fp16 MFMA, operands pre-shuffled to fragment-lane order (1KB coalesced frag
// loads). BQ=32, 512 blocks -> 2 blocks/CU under a 128-VGPR budget.
// ---------------------------------------------------------------------------

typedef __attribute__((ext_vector_type(8))) _Float16 half8;   // MFMA A/B frag
typedef __attribute__((ext_vector_type(2))) _Float16 half2;
typedef __attribute__((ext_vector_type(4))) float    floatx4; // MFMA C/D frag

#define NBATCH 8
#define SEQ    2048
#define EDIM   512
static constexpr size_t NE = (size_t)NBATCH * SEQ * EDIM;  // 8388608 elems/tensor

// Barrier WITHOUT vmcnt drain: LDS ordering only; global loads in flight stay
// in flight across it (consumers get compiler-inserted vmcnt waits). The
// memory clobber also pins surrounding loads/stores on their side of it.
__device__ __forceinline__ void block_sync_lds() {
  asm volatile("s_waitcnt lgkmcnt(0)\n\ts_barrier" ::: "memory");
}

// ---------------------------------------------------------------------------
// Fragment layout contract:
//  A/B-frag 16x16x32: lane l holds [dim16 = l&15][k = (l>>4)*8 + j].
//  Q/K: xf[((n*128 + rt)*16 + est)*512 + lane*8 + j]   (rt = row>>4, est = e>>5)
//  V:   vf[((n*64 + kt)*32 + et)*512 + lane*8 + j]     (kt = krow>>5, et = e>>4,
//        dim16 = e-col, k = krow within 32-tile)
// ---------------------------------------------------------------------------

// --- fused pre-pass: blocks [0,2048) Q/K direct gather; [2048,2560) V transpose.
__global__ void make_frags(const float* __restrict__ q, const float* __restrict__ k,
                           const float* __restrict__ v,
                           _Float16* __restrict__ qf, _Float16* __restrict__ kf,
                           _Float16* __restrict__ vf) {
  const int tid = threadIdx.x;
  if (blockIdx.x < 2048) {
#pragma unroll
    for (int i = 0; i < 4; i++) {
      const uint32_t c = blockIdx.x * 1024u + i * 256u + tid;
      const uint32_t ln = c & 63u, idx = c >> 6;
      const uint32_t est = idx & 15u, rt = (idx >> 4) & 127u;
      const uint32_t n = (idx >> 11) & 7u, tensor = idx >> 14;
      const float* src = (tensor ? k : q) +
          ((size_t)(n * SEQ + rt * 16 + (ln & 15u))) * EDIM + est * 32 + (ln >> 4) * 8;
      float4 a = *reinterpret_cast<const float4*>(src);
      float4 b = *reinterpret_cast<const float4*>(src + 4);
      half8 h;
      h[0] = (_Float16)a.x; h[1] = (_Float16)a.y; h[2] = (_Float16)a.z; h[3] = (_Float16)a.w;
      h[4] = (_Float16)b.x; h[5] = (_Float16)b.y; h[6] = (_Float16)b.z; h[7] = (_Float16)b.w;
      // c & 0xFFFFF: per-tensor chunk index (bit 20 = tensor selector — must
      // NOT leak into the offset; leaking it was the R4/R5 correctness bug).
      *reinterpret_cast<half8*>((tensor ? kf : qf) + (size_t)(c & 0xFFFFFu) * 8) = h;
    }
  } else {
    __shared__ float lds[32][260];
    const int b2 = blockIdx.x - 2048;       // 8 n x 64 kt
    const int n = b2 >> 6, kt = b2 & 63;
    const float* src = v + ((size_t)n * SEQ + kt * 32) * EDIM;
    _Float16* dst = vf + ((size_t)(n * 64 + kt) * 32) * 512;
#pragma unroll
    for (int eh = 0; eh < 2; eh++) {
      if (eh) __syncthreads();
#pragma unroll
      for (int i = 0; i < 8; i++) {         // stage 32 rows x 256 f32
        int c = i * 256 + tid;
        int row = c >> 6, col4 = c & 63;
        float4 x = *reinterpret_cast<const float4*>(src + (size_t)row * EDIM + eh * 256 + col4 * 4);
        *reinterpret_cast<float4*>(&lds[row][col4 * 4]) = x;
      }
      __syncthreads();
#pragma unroll
      for (int i = 0; i < 4; i++) {         // emit frag chunks
        int fl = i * 256 + tid;
        int etl = fl >> 6, ln = fl & 63;
        int m15 = ln & 15, q4 = ln >> 4;
        int e_local = etl * 16 + m15;
        half8 h;
#pragma unroll
        for (int j = 0; j < 8; j++) h[j] = (_Float16)lds[q4 * 8 + j][e_local];
        *reinterpret_cast<half8*>(dst + ((size_t)eh * 1024 + fl) * 8) = h;
      }
    }
  }
}

// ---------------------------------------------------------------------------
// Fused flash attention. Grid 512 = (n = blk&7, qt = blk>>3), 512 thr / 8 waves.
// BQ=32, BK=32, 64 K-tiles. Wave = (ks = w&1, es = w>>1):
//   S: both 16-q strips x its 16-krow half x 128-e quarter (K frags no-dup).
//   softmax: 32 rows x 16 thr, 2 cols each; 4-plane combine.
//   PV: wave owns 64-e slice (et = w*4..w*4+3).
// Per tile: S(kcur) -> issue K(t+1),V(t) -> s_part -> b1 -> softmax -> b2
//           -> PV(vfr).  Prefetches pinned before b1 by the asm barrier, so
// K is loaded a full tile ahead and V a full phase ahead of use.
// LDS: 18432 + 2560 + 384 = 21376 B. __launch_bounds__(512,4) caps VGPR at
// 128 -> 2 blocks/CU.
// ---------------------------------------------------------------------------
__launch_bounds__(512, 4)
__global__ void attn_fused(const _Float16* __restrict__ qf, const _Float16* __restrict__ kf,
                           const _Float16* __restrict__ vf, float* __restrict__ out) {
  __shared__ float    s_part[4][32][36];   // 4 e-quarter partial scores
  __shared__ _Float16 p_lds[32][40];       // P fp16 (A-layout source)
  __shared__ float    m_lds[32], l_lds[32], a_lds[32];

  const int tid  = threadIdx.x;
  const int lane = tid & 63, w = tid >> 6;
  const int m15  = lane & 15, q4 = lane >> 4;
  const int n    = blockIdx.x & 7, qt = blockIdx.x >> 3;   // qt 0..63
  const int ks   = w & 1, es = w >> 1;

  if (tid < 32) { m_lds[tid] = -3.0e38f; l_lds[tid] = 0.0f; }

  // ---- Q fragments resident: 2 strips x 4 est (this wave's e-quarter). 32 VGPR.
  half8 qfr[2][4];
  {
    const uint32_t qbase = ((uint32_t)(n * 128 + qt * 2) * 16 + es * 4) * 512 + (uint32_t)lane * 8;
#pragma unroll
    for (int s = 0; s < 2; s++)
#pragma unroll
      for (int i = 0; i < 4; i++)
        qfr[s][i] = *reinterpret_cast<const half8*>(qf + qbase + (uint32_t)(s * 16 + i) * 512);
  }

  floatx4 oacc[2][4];                       // [strip][et_local], 32 regs (acc)
#pragma unroll
  for (int s = 0; s < 2; s++)
#pragma unroll
    for (int j = 0; j < 4; j++) oacc[s][j] = (floatx4){0.f, 0.f, 0.f, 0.f};

  uint32_t koff = ((uint32_t)(n * 128 + ks) * 16 + es * 4) * 512 + (uint32_t)lane * 8;
  uint32_t voff = ((uint32_t)(n * 64) * 32 + w * 4) * 512 + (uint32_t)lane * 8;

  block_sync_lds();                         // covers m/l init

  // ---- K double-buffer: K(0) now; K(t+1) issued inside tile t.
  half8 kbA[4], kbB[4];
#pragma unroll
  for (int i = 0; i < 4; i++)
    kbA[i] = *reinterpret_cast<const half8*>(kf + koff + (uint32_t)i * 512);
  koff += 16384;                            // -> K(1)

  auto step = [&](int t, half8 (&kcur)[4], half8 (&knxt)[4]) {
    // ---- S phase on the prefetched buffer
    floatx4 sacc[2];
    sacc[0] = (floatx4){0.f, 0.f, 0.f, 0.f};
    sacc[1] = (floatx4){0.f, 0.f, 0.f, 0.f};
#pragma unroll
    for (int i = 0; i < 4; i++) {
      sacc[0] = __builtin_amdgcn_mfma_f32_16x16x32_f16(qfr[0][i], kcur[i], sacc[0], 0, 0, 0);
      sacc[1] = __builtin_amdgcn_mfma_f32_16x16x32_f16(qfr[1][i], kcur[i], sacc[1], 0, 0, 0);
    }
    // ---- issue K(t+1) and V(t) NOW; pinned before b1, consumed much later
    if (t < 63) {
#pragma unroll
      for (int i = 0; i < 4; i++)
        knxt[i] = *reinterpret_cast<const half8*>(kf + koff + (uint32_t)i * 512);
      koff += 16384;
    }
    half8 vfr[4];
#pragma unroll
    for (int j = 0; j < 4; j++)
      vfr[j] = *reinterpret_cast<const half8*>(vf + voff + (uint32_t)j * 512);
    voff += 16384;                          // 32 et * 512

    // ---- write S partials (C-layout: row = q4*4+r, col = m15)
#pragma unroll
    for (int s = 0; s < 2; s++)
#pragma unroll
      for (int r = 0; r < 4; r++)
        s_part[es][s * 16 + q4 * 4 + r][ks * 16 + m15] = sacc[s][r];
    block_sync_lds();                       // b1

    // ---- softmax: 32 rows x 16 threads, 2 cols each
    {
      const int r = tid >> 4, sub = tid & 15, c = sub * 2;
      float svx = s_part[0][r][c],     svy = s_part[0][r][c + 1];
#pragma unroll
      for (int pl = 1; pl < 4; pl++) { svx += s_part[pl][r][c]; svy += s_part[pl][r][c + 1]; }
      float mx = fmaxf(svx, svy);
#pragma unroll
      for (int o = 1; o < 16; o <<= 1) mx = fmaxf(mx, __shfl_xor(mx, o));
      const float mo = m_lds[r];
      const float mn = fmaxf(mo, mx);
      const float px = __expf(svx - mn), py = __expf(svy - mn);
      float rs = px + py;
#pragma unroll
      for (int o = 1; o < 16; o <<= 1) rs += __shfl_xor(rs, o);
      if (sub == 0) {
        const float al = __expf(mo - mn);
        a_lds[r] = al; m_lds[r] = mn; l_lds[r] = l_lds[r] * al + rs;
      }
      half2 ph; ph[0] = (_Float16)px; ph[1] = (_Float16)py;
      *reinterpret_cast<half2*>(&p_lds[r][c]) = ph;
    }
    block_sync_lds();                       // b2

    // ---- PV phase: V already in registers; P A-frags from LDS; rescale; MFMA
    half8 pfr[2];
    pfr[0] = *reinterpret_cast<const half8*>(&p_lds[m15][q4 * 8]);
    pfr[1] = *reinterpret_cast<const half8*>(&p_lds[16 + m15][q4 * 8]);
    {
      floatx4 al0 = *reinterpret_cast<floatx4*>(&a_lds[q4 * 4]);
      floatx4 al1 = *reinterpret_cast<floatx4*>(&a_lds[16 + q4 * 4]);
#pragma unroll
      for (int j = 0; j < 4; j++) { oacc[0][j] *= al0; oacc[1][j] *= al1; }
    }
#pragma unroll
    for (int j = 0; j < 4; j++) {
      oacc[0][j] = __builtin_amdgcn_mfma_f32_16x16x32_f16(pfr[0], vfr[j], oacc[0][j], 0, 0, 0);
      oacc[1][j] = __builtin_amdgcn_mfma_f32_16x16x32_f16(pfr[1], vfr[j], oacc[1][j], 0, 0, 0);
    }
  };

  for (int tt = 0; tt < 32; tt++) {
    step(2 * tt,     kbA, kbB);
    step(2 * tt + 1, kbB, kbA);
  }

  // ---- epilogue: divide by l, store fp32 (l_lds final after last b2)
  const int q0 = qt * 32;
#pragma unroll
  for (int s = 0; s < 2; s++) {
    floatx4 lv = *reinterpret_cast<floatx4*>(&l_lds[s * 16 + q4 * 4]);
#pragma unroll
    for (int j = 0; j < 4; j++) {
      const int col = (w * 4 + j) * 16 + m15;
#pragma unroll
      for (int r = 0; r < 4; r++) {
        const int row = s * 16 + q4 * 4 + r;
        out[((size_t)n * SEQ + q0 + row) * EDIM + col] = oacc[s][j][r] / lv[r];
      }
    }
  }
}

// ---------------------------------------------------------------------------
// Fallback (ws too small): fp32 VALU attention, one block per query row.
// ---------------------------------------------------------------------------
__global__ void attn_fallback(const float* __restrict__ q, const float* __restrict__ k,
                              const float* __restrict__ v, float* __restrict__ out) {
  __shared__ float qrow[EDIM];
  __shared__ float sc[SEQ];
  __shared__ float red[16];
  const int tid = threadIdx.x;                    // 256
  const int n = blockIdx.x >> 11, qi = blockIdx.x & 2047;
  const int wv = tid >> 6, ln = tid & 63;
  const float* qp = q + ((size_t)n * SEQ + qi) * EDIM;
  for (int e = tid; e < EDIM; e += 256) qrow[e] = qp[e];
  __syncthreads();
  for (int kk = wv; kk < SEQ; kk += 4) {
    const float* kp = k + ((size_t)n * SEQ + kk) * EDIM;
    float s = 0.f;
    for (int e = ln; e < EDIM; e += 64) s = fmaf(qrow[e], kp[e], s);
    for (int o = 32; o > 0; o >>= 1) s += __shfl_down(s, o);
    if (ln == 0) sc[kk] = s;
  }
  __syncthreads();
  float mx = -3.0e38f;
  for (int kk = tid; kk < SEQ; kk += 256) mx = fmaxf(mx, sc[kk]);
  for (int o = 32; o > 0; o >>= 1) mx = fmaxf(mx, __shfl_down(mx, o));
  if (ln == 0) red[wv] = mx;
  __syncthreads();
  if (tid == 0) {
    float m2 = red[0];
    for (int i = 1; i < 4; i++) m2 = fmaxf(m2, red[i]);
    red[8] = m2;
  }
  __syncthreads();
  const float m = red[8];
  float ls = 0.f;
  for (int kk = tid; kk < SEQ; kk += 256) { float p = __expf(sc[kk] - m); sc[kk] = p; ls += p; }
  for (int o = 32; o > 0; o >>= 1) ls += __shfl_down(ls, o);
  if (ln == 0) red[wv] = ls;
  __syncthreads();
  if (tid == 0) { red[9] = red[0] + red[1] + red[2] + red[3]; }
  __syncthreads();
  const float linv = 1.f / red[9];
  for (int e = tid; e < EDIM; e += 256) {
    float acc = 0.f;
    const float* vp = v + ((size_t)n * SEQ) * EDIM + e;
    for (int kk = 0; kk < SEQ; kk++) acc = fmaf(sc[kk], vp[(size_t)kk * EDIM], acc);
    out[((size_t)n * SEQ + qi) * EDIM + e] = acc * linv;
  }
}

extern "C" void kernel_launch(void* const* d_in, const int* in_sizes, int n_in,
                              void* d_out, int out_size, void* d_ws, size_t ws_size,
                              hipStream_t stream) {
  const float* q = (const float*)d_in[0];
  const float* k = (const float*)d_in[1];
  const float* v = (const float*)d_in[2];
  float* out = (float*)d_out;
  const size_t need = 3 * NE * sizeof(_Float16);   // 50.3 MB
  if (ws_size >= need) {
    _Float16* qf = (_Float16*)d_ws;
    _Float16* kf = qf + NE;
    _Float16* vf = kf + NE;
    make_frags<<<2560, 256, 0, stream>>>(q, k, v, qf, kf, vf);
    attn_fused<<<512, 512, 0, stream>>>(qf, kf, vf, out);
  } else {
    attn_fallback<<<16384, 256, 0, stream>>>(q, k, v, out);
  }
}